// Round 2
// baseline (932.498 us; speedup 1.0000x reference)
//
#include <hip/hip_runtime.h>

#define N_NODES 100000
#define N_EDGES 3200000
#define F_IN 128
#define F_OUT 16

// ws layout: dinv (N floats) at byte 0; h (N*F_OUT floats) at byte OFF_H
#define OFF_H (1u << 19)  // 512 KiB > 400 KB deg array

typedef float v2f __attribute__((ext_vector_type(2)));

// Packed v2f32 atomic add with graceful degradation.
__device__ __forceinline__ void atomic_pk_add2(float* addr, float a, float b) {
#if defined(__has_builtin) && __has_builtin(__builtin_amdgcn_global_atomic_fadd_v2f32)
    v2f v = {a, b};
    __builtin_amdgcn_global_atomic_fadd_v2f32(
        (__attribute__((address_space(1))) v2f*)addr, v);
#elif defined(__has_builtin) && __has_builtin(__builtin_amdgcn_flat_atomic_fadd_v2f32)
    v2f v = {a, b};
    __builtin_amdgcn_flat_atomic_fadd_v2f32((v2f*)addr, v);
#else
    atomicAdd(addr, a);
    atomicAdd(addr + 1, b);
#endif
}

// K1: deg starts at 1.0 (self-loop weight)
__global__ void k_init_deg(float* __restrict__ deg) {
    int i = blockIdx.x * blockDim.x + threadIdx.x;
    if (i < N_NODES) deg[i] = 1.0f;
}

// K2: deg[col[e]] += w[e]
__global__ void k_accum_deg(const int* __restrict__ col,
                            const float* __restrict__ ew,
                            float* __restrict__ deg) {
    int e = blockIdx.x * blockDim.x + threadIdx.x;
    if (e < N_EDGES) atomicAdd(&deg[col[e]], ew[e]);
}

// K3: dinv = rsqrt(deg)  (deg >= 1 always; in-place)
__global__ void k_dinv(float* __restrict__ deg) {
    int i = blockIdx.x * blockDim.x + threadIdx.x;
    if (i < N_NODES) deg[i] = rsqrtf(deg[i]);
}

// K4: h = x @ W  and  out = b + h * dinv^2  (self-loop contribution)
// 256 threads = 16 rows/block, lane j = output feature; W staged in LDS (8 KB)
__global__ void k_gemm_init(const float* __restrict__ x,
                            const float* __restrict__ W,
                            const float* __restrict__ b,
                            const float* __restrict__ dinv,
                            float* __restrict__ h,
                            float* __restrict__ out) {
    __shared__ float Ws[F_IN * F_OUT];
    int tid = threadIdx.x;
    for (int i = tid; i < F_IN * F_OUT; i += 256) Ws[i] = W[i];
    __syncthreads();

    int n = blockIdx.x * 16 + (tid >> 4);
    int j = tid & 15;
    if (n >= N_NODES) return;

    const float4* xr = (const float4*)(x + (size_t)n * F_IN);
    float acc = 0.0f;
#pragma unroll
    for (int k4 = 0; k4 < F_IN / 4; ++k4) {
        float4 xv = xr[k4];
        int k = k4 * 4;
        acc += xv.x * Ws[(k + 0) * F_OUT + j];
        acc += xv.y * Ws[(k + 1) * F_OUT + j];
        acc += xv.z * Ws[(k + 2) * F_OUT + j];
        acc += xv.w * Ws[(k + 3) * F_OUT + j];
    }
    h[n * F_OUT + j] = acc;
    float di = dinv[n];
    out[n * F_OUT + j] = b[j] + acc * di * di;
}

// K5: scatter — 4 lanes per edge; lane q loads float4 of h, issues 2 packed
// v2f32 atomics. Atomic op count: 2 per lane * 12.8M lanes = 25.6M (was 51.2M).
__global__ void k_scatter(const int* __restrict__ row,
                          const int* __restrict__ col,
                          const float* __restrict__ ew,
                          const float* __restrict__ dinv,
                          const float* __restrict__ h,
                          float* __restrict__ out) {
    long long tid = (long long)blockIdx.x * blockDim.x + threadIdx.x;
    int e = (int)(tid >> 2);
    int q = (int)(tid & 3);
    if (e >= N_EDGES) return;
    int r = row[e];
    int c = col[e];
    float norm = dinv[r] * ew[e] * dinv[c];
    float4 hv = ((const float4*)h)[(size_t)r * 4 + q];
    float* dst = out + (size_t)c * F_OUT + q * 4;
    atomic_pk_add2(dst,     hv.x * norm, hv.y * norm);
    atomic_pk_add2(dst + 2, hv.z * norm, hv.w * norm);
}

extern "C" void kernel_launch(void* const* d_in, const int* in_sizes, int n_in,
                              void* d_out, int out_size, void* d_ws, size_t ws_size,
                              hipStream_t stream) {
    const float* x  = (const float*)d_in[0];
    const int*   ei = (const int*)d_in[1];   // [2, N_EDGES] int32
    const float* ew = (const float*)d_in[2];
    const float* W  = (const float*)d_in[3];
    const float* b  = (const float*)d_in[4];
    float* out = (float*)d_out;

    const int* row = ei;            // edge_index[0] = source
    const int* col = ei + N_EDGES;  // edge_index[1] = destination

    float* dinv = (float*)d_ws;
    float* h    = (float*)((char*)d_ws + OFF_H);

    dim3 blk(256);
    k_init_deg<<<(N_NODES + 255) / 256, blk, 0, stream>>>(dinv);
    k_accum_deg<<<(N_EDGES + 255) / 256, blk, 0, stream>>>(col, ew, dinv);
    k_dinv<<<(N_NODES + 255) / 256, blk, 0, stream>>>(dinv);
    k_gemm_init<<<(N_NODES + 15) / 16, blk, 0, stream>>>(x, W, b, dinv, h, out);

    long long total = (long long)N_EDGES * 4;
    k_scatter<<<(unsigned)((total + 255) / 256), blk, 0, stream>>>(row, col, ew, dinv, h, out);
}

// Round 3
// 657.461 us; speedup vs baseline: 1.4183x; 1.4183x over previous
//
#include <hip/hip_runtime.h>

#define N_NODES 100000
#define N_EDGES 3200000
#define F_IN 128
#define F_OUT 16
#define SCAN_BLOCKS ((N_NODES + 255) / 256)   // 391

// ws layout (bytes)
#define OFF_DEG   0u            // N floats (deg -> dinv in place), 400 KB
#define OFF_CNT   (1u << 19)    // N ints, 400 KB
#define OFF_RPTR  (1u << 20)    // N+1 ints
#define OFF_CUR   ((1u << 20) + (1u << 19))  // N ints
#define OFF_PART  (2u << 20)    // 512 ints
#define OFF_H     (4u << 20)    // N*16 floats, 6.4 MB
#define OFF_CSR   (16u << 20)   // E int2 (src, norm-bits), 25.6 MB
#define WS_NEEDED ((size_t)(16u << 20) + (size_t)N_EDGES * 8)

// ---------- shared small kernels ----------

__global__ void k_init(float* __restrict__ deg, int* __restrict__ cnt) {
    int i = blockIdx.x * blockDim.x + threadIdx.x;
    if (i < N_NODES) { deg[i] = 1.0f; cnt[i] = 0; }
}

__global__ void k_accum(const int* __restrict__ col,
                        const float* __restrict__ ew,
                        float* __restrict__ deg,
                        int* __restrict__ cnt) {
    int e = blockIdx.x * blockDim.x + threadIdx.x;
    if (e < N_EDGES) {
        int c = col[e];
        atomicAdd(&deg[c], ew[e]);
        atomicAdd(&cnt[c], 1);
    }
}

// scan A: per-block exclusive scan of cnt -> rptr(local); block total -> part;
// fused: dinv = rsqrt(deg)
__global__ void k_scan_a(const int* __restrict__ cnt,
                         int* __restrict__ rptr,
                         int* __restrict__ part,
                         float* __restrict__ deg) {
    __shared__ int s[256];
    int tid = threadIdx.x;
    int i = blockIdx.x * 256 + tid;
    int v = (i < N_NODES) ? cnt[i] : 0;
    if (i < N_NODES) deg[i] = rsqrtf(deg[i]);   // deg -> dinv in place
    s[tid] = v;
    __syncthreads();
    for (int off = 1; off < 256; off <<= 1) {
        int t = (tid >= off) ? s[tid - off] : 0;
        __syncthreads();
        s[tid] += t;
        __syncthreads();
    }
    if (i < N_NODES) rptr[i] = s[tid] - v;      // exclusive
    if (tid == 255) part[blockIdx.x] = s[255];
}

// scan B: single block scans the 391 block totals (exclusive, in place)
__global__ void k_scan_b(int* __restrict__ part) {
    __shared__ int s[512];
    int tid = threadIdx.x;
    int v = (tid < SCAN_BLOCKS) ? part[tid] : 0;
    s[tid] = v;
    __syncthreads();
    for (int off = 1; off < 512; off <<= 1) {
        int t = (tid >= off) ? s[tid - off] : 0;
        __syncthreads();
        s[tid] += t;
        __syncthreads();
    }
    if (tid < SCAN_BLOCKS) part[tid] = s[tid] - v;  // exclusive
}

// scan C: add block offsets; init cursor; write rptr[N] = E
__global__ void k_scan_c(int* __restrict__ rptr,
                         int* __restrict__ cur,
                         const int* __restrict__ part) {
    int i = blockIdx.x * 256 + threadIdx.x;
    if (i < N_NODES) {
        int r = rptr[i] + part[blockIdx.x];
        rptr[i] = r;
        cur[i] = r;
    }
    if (i == 0) rptr[N_NODES] = N_EDGES;
}

__global__ void k_fill_csr(const int* __restrict__ row,
                           const int* __restrict__ col,
                           const float* __restrict__ ew,
                           const float* __restrict__ dinv,
                           int* __restrict__ cur,
                           int2* __restrict__ csr) {
    int e = blockIdx.x * blockDim.x + threadIdx.x;
    if (e < N_EDGES) {
        int r = row[e];
        int c = col[e];
        float norm = dinv[r] * ew[e] * dinv[c];
        int pos = atomicAdd(&cur[c], 1);
        int2 v;
        v.x = r;
        v.y = __float_as_int(norm);
        csr[pos] = v;
    }
}

// h = x @ W ; out = b + h*dinv^2 (self-loop term). 16 rows/block, lane j = feature.
__global__ void k_gemm_init(const float* __restrict__ x,
                            const float* __restrict__ W,
                            const float* __restrict__ b,
                            const float* __restrict__ dinv,
                            float* __restrict__ h,
                            float* __restrict__ out) {
    __shared__ float Ws[F_IN * F_OUT];
    int tid = threadIdx.x;
    for (int i = tid; i < F_IN * F_OUT; i += 256) Ws[i] = W[i];
    __syncthreads();

    int n = blockIdx.x * 16 + (tid >> 4);
    int j = tid & 15;
    if (n >= N_NODES) return;

    const float4* xr = (const float4*)(x + (size_t)n * F_IN);
    float acc = 0.0f;
#pragma unroll
    for (int k4 = 0; k4 < F_IN / 4; ++k4) {
        float4 xv = xr[k4];
        int k = k4 * 4;
        acc += xv.x * Ws[(k + 0) * F_OUT + j];
        acc += xv.y * Ws[(k + 1) * F_OUT + j];
        acc += xv.z * Ws[(k + 2) * F_OUT + j];
        acc += xv.w * Ws[(k + 3) * F_OUT + j];
    }
    h[n * F_OUT + j] = acc;
    float di = dinv[n];
    out[n * F_OUT + j] = b[j] + acc * di * di;
}

// pull: one wave per destination node; lane = (q,j), q = edge-slot (4-way), j = feature.
// No atomics: each node's 16 outputs owned by lanes q==0.
__global__ void k_pull(const int* __restrict__ rptr,
                       const int2* __restrict__ csr,
                       const float* __restrict__ h,
                       float* __restrict__ out) {
    int wave = threadIdx.x >> 6;
    int lane = threadIdx.x & 63;
    int c = blockIdx.x * 4 + wave;
    if (c >= N_NODES) return;
    int q = lane >> 4;
    int j = lane & 15;
    int p0 = rptr[c];
    int p1 = rptr[c + 1];
    float acc = 0.0f;
    for (int p = p0 + q; p < p1; p += 4) {
        int2 e = csr[p];
        acc += h[(size_t)e.x * F_OUT + j] * __int_as_float(e.y);
    }
    acc += __shfl_xor(acc, 16);
    acc += __shfl_xor(acc, 32);
    if (q == 0) out[(size_t)c * F_OUT + j] += acc;
}

// ---------- fallback (R1 path): direct atomic scatter ----------

__global__ void k_scatter_fb(const int* __restrict__ row,
                             const int* __restrict__ col,
                             const float* __restrict__ ew,
                             const float* __restrict__ dinv,
                             const float* __restrict__ h,
                             float* __restrict__ out) {
    long long tid = (long long)blockIdx.x * blockDim.x + threadIdx.x;
    int e = (int)(tid >> 4);
    int j = (int)(tid & 15);
    if (e >= N_EDGES) return;
    int r = row[e];
    int c = col[e];
    float norm = dinv[r] * ew[e] * dinv[c];
    atomicAdd(&out[(size_t)c * F_OUT + j], h[(size_t)r * F_OUT + j] * norm);
}

extern "C" void kernel_launch(void* const* d_in, const int* in_sizes, int n_in,
                              void* d_out, int out_size, void* d_ws, size_t ws_size,
                              hipStream_t stream) {
    const float* x  = (const float*)d_in[0];
    const int*   ei = (const int*)d_in[1];   // [2, N_EDGES] int32
    const float* ew = (const float*)d_in[2];
    const float* W  = (const float*)d_in[3];
    const float* b  = (const float*)d_in[4];
    float* out = (float*)d_out;

    const int* row = ei;            // edge_index[0] = source
    const int* col = ei + N_EDGES;  // edge_index[1] = destination

    char* ws = (char*)d_ws;
    float* deg  = (float*)(ws + OFF_DEG);   // becomes dinv
    int*   cnt  = (int*)(ws + OFF_CNT);
    int*   rptr = (int*)(ws + OFF_RPTR);
    int*   cur  = (int*)(ws + OFF_CUR);
    int*   part = (int*)(ws + OFF_PART);
    float* h    = (float*)(ws + OFF_H);
    int2*  csr  = (int2*)(ws + OFF_CSR);

    dim3 blk(256);
    unsigned gN = (N_NODES + 255) / 256;
    unsigned gE = (N_EDGES + 255) / 256;

    if (ws_size >= WS_NEEDED) {
        k_init<<<gN, blk, 0, stream>>>(deg, cnt);
        k_accum<<<gE, blk, 0, stream>>>(col, ew, deg, cnt);
        k_scan_a<<<SCAN_BLOCKS, blk, 0, stream>>>(cnt, rptr, part, deg);
        k_scan_b<<<1, 512, 0, stream>>>(part);
        k_scan_c<<<SCAN_BLOCKS, blk, 0, stream>>>(rptr, cur, part);
        k_fill_csr<<<gE, blk, 0, stream>>>(row, col, ew, deg, cur, csr);
        k_gemm_init<<<(N_NODES + 15) / 16, blk, 0, stream>>>(x, W, b, deg, h, out);
        k_pull<<<(N_NODES + 3) / 4, blk, 0, stream>>>(rptr, csr, h, out);
    } else {
        // fallback: R1 atomic-scatter path (needs only ~7 MB of ws)
        k_init<<<gN, blk, 0, stream>>>(deg, cnt);
        k_accum<<<gE, blk, 0, stream>>>(col, ew, deg, cnt);
        k_scan_a<<<SCAN_BLOCKS, blk, 0, stream>>>(cnt, rptr, part, deg);  // for dinv
        k_gemm_init<<<(N_NODES + 15) / 16, blk, 0, stream>>>(x, W, b, deg, h, out);
        long long total = (long long)N_EDGES * F_OUT;
        k_scatter_fb<<<(unsigned)((total + 255) / 256), blk, 0, stream>>>(row, col, ew, deg, h, out);
    }
}

// Round 4
// 440.722 us; speedup vs baseline: 2.1158x; 1.4918x over previous
//
#include <hip/hip_runtime.h>

#define N_NODES 100000
#define N_EDGES 3200000
#define F_IN 128
#define F_OUT 16

#define EDGE_BLOCKS ((N_EDGES + 255) / 256)   // 12500
#define GEMM_BLOCKS ((N_NODES + 15) / 16)     // 6250  (== EDGE_BLOCKS/2 exactly)

// ws layout: deg/dinv @0 (400 KB) ; h @1 MB (6.4 MB) ; g @8 MB (6.4 MB)
#define OFF_H (1u << 20)
#define OFF_G (8u << 20)

// K1: deg = 1.0 (self-loop weight folded in)
__global__ void k_init(float* __restrict__ deg) {
    int i = blockIdx.x * blockDim.x + threadIdx.x;
    if (i < N_NODES) deg[i] = 1.0f;
}

// K2: fused  deg[col[e]] += ew[e]  (atomic-rate bound)  +  h = x@W (BW/VALU bound).
// 2:1 interleave matches the 12500:6250 block ratio so both kinds co-run on
// every CU — the GEMM hides inside the atomic pass.
__global__ void k_fused(const int* __restrict__ col,
                        const float* __restrict__ ew,
                        float* __restrict__ deg,
                        const float* __restrict__ x,
                        const float* __restrict__ W,
                        float* __restrict__ h) {
    int b3 = blockIdx.x / 3;
    int r3 = blockIdx.x % 3;
    if (r3 < 2) {
        // edge-accum block (12500 of these)
        int eb = b3 * 2 + r3;
        int e = eb * 256 + threadIdx.x;
        if (e < N_EDGES) atomicAdd(&deg[col[e]], ew[e]);
    } else {
        // gemm block (6250 of these): 16 rows, lane j = output feature
        __shared__ float Ws[F_IN * F_OUT];
        int tid = threadIdx.x;
        for (int i = tid; i < F_IN * F_OUT; i += 256) Ws[i] = W[i];
        __syncthreads();

        int n = b3 * 16 + (tid >> 4);
        int j = tid & 15;
        if (n >= N_NODES) return;

        const float4* xr = (const float4*)(x + (size_t)n * F_IN);
        float acc = 0.0f;
#pragma unroll
        for (int k4 = 0; k4 < F_IN / 4; ++k4) {
            float4 xv = xr[k4];
            int k = k4 * 4;
            acc += xv.x * Ws[(k + 0) * F_OUT + j];
            acc += xv.y * Ws[(k + 1) * F_OUT + j];
            acc += xv.z * Ws[(k + 2) * F_OUT + j];
            acc += xv.w * Ws[(k + 3) * F_OUT + j];
        }
        h[(size_t)n * F_OUT + j] = acc;
    }
}

// K3: finalize — dinv = rsqrt(deg) (stored back into deg, wave-synchronous),
// g = dinv*h, out = b + dinv*g (self-loop term).
__global__ void k_final(float* __restrict__ deg,
                        const float* __restrict__ h,
                        const float* __restrict__ b,
                        float* __restrict__ g,
                        float* __restrict__ out) {
    int i = blockIdx.x * blockDim.x + threadIdx.x;  // i = n*16 + j
    int n = i >> 4;
    int j = i & 15;
    if (n >= N_NODES) return;
    float d = rsqrtf(deg[n]);     // all 16 lanes of n are in one wave: reads
    if (j == 0) deg[n] = d;       // complete before this lockstep write
    float gg = d * h[i];
    g[i] = gg;
    out[i] = b[j] + d * gg;
}

// K4: scatter — 16 lanes/edge; norm = ew * dinv[c] (dinv[r] pre-folded into g).
// One coalesced 64 B atomic group per edge -> 1 line-transaction/edge.
__global__ void k_scatter(const int* __restrict__ row,
                          const int* __restrict__ col,
                          const float* __restrict__ ew,
                          const float* __restrict__ dinv,
                          const float* __restrict__ g,
                          float* __restrict__ out) {
    long long tid = (long long)blockIdx.x * blockDim.x + threadIdx.x;
    int e = (int)(tid >> 4);
    int j = (int)(tid & 15);
    if (e >= N_EDGES) return;
    int r = row[e];
    int c = col[e];
    float norm = ew[e] * dinv[c];
    atomicAdd(&out[(size_t)c * F_OUT + j], g[(size_t)r * F_OUT + j] * norm);
}

extern "C" void kernel_launch(void* const* d_in, const int* in_sizes, int n_in,
                              void* d_out, int out_size, void* d_ws, size_t ws_size,
                              hipStream_t stream) {
    const float* x  = (const float*)d_in[0];
    const int*   ei = (const int*)d_in[1];   // [2, N_EDGES] int32
    const float* ew = (const float*)d_in[2];
    const float* W  = (const float*)d_in[3];
    const float* b  = (const float*)d_in[4];
    float* out = (float*)d_out;

    const int* row = ei;            // edge_index[0] = source
    const int* col = ei + N_EDGES;  // edge_index[1] = destination

    char* ws = (char*)d_ws;
    float* deg = (float*)ws;              // becomes dinv after k_final
    float* h   = (float*)(ws + OFF_H);
    float* g   = (float*)(ws + OFF_G);

    dim3 blk(256);
    k_init<<<(N_NODES + 255) / 256, blk, 0, stream>>>(deg);
    k_fused<<<EDGE_BLOCKS + GEMM_BLOCKS, blk, 0, stream>>>(col, ew, deg, x, W, h);
    k_final<<<(N_NODES * F_OUT + 255) / 256, blk, 0, stream>>>(deg, h, b, g, out);
    long long total = (long long)N_EDGES * F_OUT;
    k_scatter<<<(unsigned)((total + 255) / 256), blk, 0, stream>>>(row, col, ew, deg, g, out);
}